// Round 10
// baseline (821.031 us; speedup 1.0000x reference)
//
#include <hip/hip_runtime.h>
#include <hip/hip_bf16.h>
#include <hip/hip_fp16.h>
#include <stdint.h>

#define NN 50000
#define NE 800000
#define HD 128
#define EPSN 1e-5f
#define CAP 1152000   // padded CSR capacity: NE + NN*7 rounded up
#define NPAIRS 25000
#define NCHUNK 6250   // NPAIRS / 4

typedef __hip_bfloat16 bf16;

__device__ __forceinline__ float us2f(unsigned short u) { return __uint_as_float((uint32_t)u << 16); }
__device__ __forceinline__ ushort f2us(float f) {
    bf16 b = __float2bfloat16(f);
    return *reinterpret_cast<ushort*>(&b);
}
__device__ __forceinline__ ushort f2h(float f) {
    __half h = __float2half(f);
    return *reinterpret_cast<ushort*>(&h);
}
__device__ __forceinline__ float h2f(ushort u) {
    __half h = *reinterpret_cast<__half*>(&u);
    return __half2float(h);
}

// canonical fp32 parameter block offsets
#define O_X    0
#define O_CW   100000
#define O_CB   100256
#define O_LNG  100384
#define O_LNB  100512
#define O_BNG  100640
#define O_BNB  100768
#define O_W1   100896
#define O_B1   117280
#define O_W2   117408
#define O_B2   133792
#define O_W3   133920
#define O_B3   150304
#define O_F1W  150432
#define O_F1B  154528
#define O_F2W  154560
#define O_F2B  154624
#define O_TOT  154626

struct Ptrs { const void* p[17]; };

__device__ const int SEG_OFF[18] = {O_X, O_CW, O_CB, O_LNG, O_LNB, O_BNG, O_BNB,
                                    O_W1, O_B1, O_W2, O_B2, O_W3, O_B3,
                                    O_F1W, O_F1B, O_F2W, O_F2B, O_TOT};

// Edge accessor: isL=1 -> int64 storage (read low words), else int32.
__device__ __forceinline__ int eidx(const int* __restrict__ ei, int isL, int which, int e) {
    size_t base = (size_t)which * NE + e;
    return isL ? ei[2 * base] : ei[base];
}

// ------- canonicalize floats to fp32; self-detects bf16; block 0 publishes flags -------
__global__ void k_conv(Ptrs ptrs, const int* __restrict__ ei, const ushort* __restrict__ cw,
                       float* __restrict__ cp, int* __restrict__ flags) {
    int t = threadIdx.x;
    __shared__ int sb[4], sv[4];
    int bad = 0;
    if (t < 128) {
        float val = us2f(cw[2 * t]);           // low half if f32, real weight if bf16
        bad = !(fabsf(val) <= 1.0f);           // NaN/Inf -> bad
    }
    for (int o = 32; o; o >>= 1) bad |= __shfl_xor(bad, o);
    if ((t & 63) == 0) sb[t >> 6] = bad;
    __syncthreads();
    int isB = ((sb[0] | sb[1] | sb[2] | sb[3]) == 0) ? 1 : 0;
    if (blockIdx.x == 0) {
        int v = ei[2 * t + 1] | ei[1000000 + 2 * t + 1];   // int64 -> odd words all zero
        for (int o = 32; o; o >>= 1) v |= __shfl_xor(v, o);
        if ((t & 63) == 0) sv[t >> 6] = v;
        __syncthreads();
        if (t == 0) {
            flags[0] = ((sv[0] | sv[1] | sv[2] | sv[3]) == 0) ? 1 : 0;
            flags[1] = isB;
        }
    }
    int i = blockIdx.x * 256 + t;
    if (i >= O_TOT) return;
    int s = 0;
    while (i >= SEG_OFF[s + 1]) s++;
    int local = i - SEG_OFF[s];
    const void* src = ptrs.p[s];
    cp[i] = isB ? us2f(((const ushort*)src)[local]) : ((const float*)src)[local];
}

// ---------------- graph preprocessing (deg zeroed by memset; raw = edge-only count) ------

__global__ void k_deg(const int* __restrict__ ei, const int* __restrict__ flags,
                      int* __restrict__ deg) {
    int e = blockIdx.x * 256 + threadIdx.x;
    if (e < NE) atomicAdd(&deg[eidx(ei, flags[0], 1, e)], 1);
}

__global__ void k_dinv_alloc(const int* __restrict__ deg, float* __restrict__ dinv,
                             int* __restrict__ startA, int* __restrict__ curA,
                             int* __restrict__ cursor, int2* __restrict__ srw) {
    int i = blockIdx.x * 256 + threadIdx.x;
    if (i < NN) {
        int c = deg[i];                        // edge-only in-count
        dinv[i] = rsqrtf((float)(c + 1));      // +1 self-loop
        int cpad = (c + 7) & ~7;               // pad list to multiple of 8
        int s = atomicAdd(cursor, cpad);
        startA[i] = s;
        curA[i] = s;
        for (int j = c; j < cpad; j++) srw[s + j] = make_int2(0, 0);  // sentinels w=0
    }
}

__global__ void k_fill(const int* __restrict__ ei, const int* __restrict__ flags,
                       const float* __restrict__ dinv, int* __restrict__ curA,
                       int2* __restrict__ srw) {
    int e = blockIdx.x * 256 + threadIdx.x;
    if (e >= NE) return;
    int isL = flags[0];
    int r = eidx(ei, isL, 0, e);
    int c = eidx(ei, isL, 1, e);
    int p = atomicAdd(&curA[c], 1);
    srw[p] = make_int2(r << 7, __float_as_int(dinv[r] * dinv[c]));
}

// ------- layer-0 GEMM fused with embed: u = LN(relu(x@cW+cb)); h=u; t0h=fp16(u@W) -------

__global__ __launch_bounds__(256) void k_gemm0(const float* __restrict__ cp,
                                               float* __restrict__ h,
                                               const float* __restrict__ Wf,
                                               ushort* __restrict__ t0h) {
    __shared__ float Wl[64 * HD];       // 32 KB
    __shared__ float hl[32 * HD];       // 16 KB
    __shared__ float sCW[2 * HD], sCB[HD], sLG[HD], sLB[HD];
    int t = threadIdx.x;
    sCW[t] = cp[O_CW + t];
    if (t < 128) { sCB[t] = cp[O_CB + t]; sLG[t] = cp[O_LNG + t]; sLB[t] = cp[O_LNB + t]; }
    __syncthreads();
    int nodeBase = blockIdx.x * 32;
    const float* X = cp + O_X;
    float4* h4g = (float4*)h;
    float4* hl4 = (float4*)hl;
#pragma unroll
    for (int r = 0; r < 4; r++) {
        int idx = r * 256 + t;
        int n = nodeBase + (idx >> 5);
        int c4 = idx & 31;
        int f = c4 * 4;
        float4 u = make_float4(0.f, 0.f, 0.f, 0.f);
        if (n < NN) {
            float x0 = X[n * 2], x1 = X[n * 2 + 1];
            u.x = fmaxf(0.f, x0 * sCW[f]     + x1 * sCW[HD + f]     + sCB[f]);
            u.y = fmaxf(0.f, x0 * sCW[f + 1] + x1 * sCW[HD + f + 1] + sCB[f + 1]);
            u.z = fmaxf(0.f, x0 * sCW[f + 2] + x1 * sCW[HD + f + 2] + sCB[f + 2]);
            u.w = fmaxf(0.f, x0 * sCW[f + 3] + x1 * sCW[HD + f + 3] + sCB[f + 3]);
        }
        float s = u.x + u.y + u.z + u.w;
        float q = u.x * u.x + u.y * u.y + u.z * u.z + u.w * u.w;
        for (int o = 16; o; o >>= 1) { s += __shfl_xor(s, o); q += __shfl_xor(q, o); }
        float m = s * (1.f / HD);
        float var = q * (1.f / HD) - m * m;
        float rr = rsqrtf(var + EPSN);
        u.x = (u.x - m) * rr * sLG[f]     + sLB[f];
        u.y = (u.y - m) * rr * sLG[f + 1] + sLB[f + 1];
        u.z = (u.z - m) * rr * sLG[f + 2] + sLB[f + 2];
        u.w = (u.w - m) * rr * sLG[f + 3] + sLB[f + 3];
        hl4[idx] = u;
        if (n < NN) h4g[(size_t)n * 32 + c4] = u;
    }
    int fq = t & 31;
    int ng = t >> 5;
    float4 acc[4];
#pragma unroll
    for (int j = 0; j < 4; j++) acc[j] = make_float4(0.f, 0.f, 0.f, 0.f);
    const float4* Wl4 = (const float4*)Wl;
    for (int ph = 0; ph < 2; ph++) {
        __syncthreads();
        const float4* Wg4 = (const float4*)(Wf + ph * 64 * HD);
        float4* Wld = (float4*)Wl;
#pragma unroll
        for (int r = 0; r < 8; r++) Wld[r * 256 + t] = Wg4[r * 256 + t];
        __syncthreads();
        for (int k4 = 0; k4 < 16; k4++) {
            int kb = k4 * 4;
            float4 w0 = Wl4[(kb + 0) * 32 + fq];
            float4 w1 = Wl4[(kb + 1) * 32 + fq];
            float4 w2 = Wl4[(kb + 2) * 32 + fq];
            float4 w3 = Wl4[(kb + 3) * 32 + fq];
#pragma unroll
            for (int j = 0; j < 4; j++) {
                float4 hv = hl4[(ng + 8 * j) * 32 + ph * 16 + k4];
                acc[j].x += hv.x * w0.x + hv.y * w1.x + hv.z * w2.x + hv.w * w3.x;
                acc[j].y += hv.x * w0.y + hv.y * w1.y + hv.z * w2.y + hv.w * w3.y;
                acc[j].z += hv.x * w0.z + hv.y * w1.z + hv.z * w2.z + hv.w * w3.z;
                acc[j].w += hv.x * w0.w + hv.y * w1.w + hv.z * w2.w + hv.w * w3.w;
            }
        }
    }
#pragma unroll
    for (int j = 0; j < 4; j++) {
        int n = nodeBase + ng + 8 * j;
        if (n < NN) {
            ushort4 o;
            o.x = f2h(acc[j].x); o.y = f2h(acc[j].y);
            o.z = f2h(acc[j].z); o.w = f2h(acc[j].w);
            ((ushort4*)(t0h + (size_t)n * HD))[fq] = o;
        }
    }
}

// ------- fused BN+residual+InstanceNorm + GEMM (layers 1,2) -------

__global__ __launch_bounds__(256) void k_gemm_fused(const float* __restrict__ agg,
                                                    const float* __restrict__ stats,
                                                    const float* __restrict__ bias,
                                                    const float* __restrict__ bng,
                                                    const float* __restrict__ bnb,
                                                    float* __restrict__ h,
                                                    const float* __restrict__ Wf,
                                                    ushort* __restrict__ t0h) {
    __shared__ float Wl[64 * HD];       // 32 KB
    __shared__ float hl[32 * HD];       // 16 KB
    __shared__ float scL[HD], shL[HD], bL[HD];
    int t = threadIdx.x;
    if (t < 128) {
        const float invN = 1.f / NN;
        float m = stats[t] * invN;
        float v = stats[128 + t] * invN - m * m;
        float sc = bng[t] * rsqrtf(v + EPSN);
        scL[t] = sc;
        shL[t] = bnb[t] - m * sc;
        bL[t] = bias[t];
    }
    __syncthreads();
    int nodeBase = blockIdx.x * 32;
    const float4* a4 = (const float4*)agg;
    float4* h4g = (float4*)h;
    float4* hl4 = (float4*)hl;
#pragma unroll
    for (int r = 0; r < 4; r++) {
        int idx = r * 256 + t;
        int n = nodeBase + (idx >> 5);
        int c4 = idx & 31;
        float4 u = make_float4(0.f, 0.f, 0.f, 0.f);
        if (n < NN) {
            float4 av = a4[(size_t)n * 32 + c4];
            float4 hv = h4g[(size_t)n * 32 + c4];
            int f = c4 * 4;
            float y0 = fmaxf(0.f, av.x + bL[f]);
            float y1 = fmaxf(0.f, av.y + bL[f + 1]);
            float y2 = fmaxf(0.f, av.z + bL[f + 2]);
            float y3 = fmaxf(0.f, av.w + bL[f + 3]);
            u.x = y0 * scL[f]     + shL[f]     + hv.x;
            u.y = y1 * scL[f + 1] + shL[f + 1] + hv.y;
            u.z = y2 * scL[f + 2] + shL[f + 2] + hv.z;
            u.w = y3 * scL[f + 3] + shL[f + 3] + hv.w;
        }
        float s = u.x + u.y + u.z + u.w;
        float q = u.x * u.x + u.y * u.y + u.z * u.z + u.w * u.w;
        for (int o = 16; o; o >>= 1) { s += __shfl_xor(s, o); q += __shfl_xor(q, o); }
        float m = s * (1.f / HD);
        float var = q * (1.f / HD) - m * m;
        float rr = rsqrtf(var + EPSN);
        u.x = (u.x - m) * rr; u.y = (u.y - m) * rr;
        u.z = (u.z - m) * rr; u.w = (u.w - m) * rr;
        hl4[idx] = u;
        if (n < NN) h4g[(size_t)n * 32 + c4] = u;
    }
    int fq = t & 31;
    int ng = t >> 5;
    float4 acc[4];
#pragma unroll
    for (int j = 0; j < 4; j++) acc[j] = make_float4(0.f, 0.f, 0.f, 0.f);
    const float4* Wl4 = (const float4*)Wl;
    for (int ph = 0; ph < 2; ph++) {
        __syncthreads();
        const float4* Wg4 = (const float4*)(Wf + ph * 64 * HD);
        float4* Wld = (float4*)Wl;
#pragma unroll
        for (int r = 0; r < 8; r++) Wld[r * 256 + t] = Wg4[r * 256 + t];
        __syncthreads();
        for (int k4 = 0; k4 < 16; k4++) {
            int kb = k4 * 4;
            float4 w0 = Wl4[(kb + 0) * 32 + fq];
            float4 w1 = Wl4[(kb + 1) * 32 + fq];
            float4 w2 = Wl4[(kb + 2) * 32 + fq];
            float4 w3 = Wl4[(kb + 3) * 32 + fq];
#pragma unroll
            for (int j = 0; j < 4; j++) {
                float4 hv = hl4[(ng + 8 * j) * 32 + ph * 16 + k4];
                acc[j].x += hv.x * w0.x + hv.y * w1.x + hv.z * w2.x + hv.w * w3.x;
                acc[j].y += hv.x * w0.y + hv.y * w1.y + hv.z * w2.y + hv.w * w3.y;
                acc[j].z += hv.x * w0.z + hv.y * w1.z + hv.z * w2.z + hv.w * w3.z;
                acc[j].w += hv.x * w0.w + hv.y * w1.w + hv.z * w2.w + hv.w * w3.w;
            }
        }
    }
#pragma unroll
    for (int j = 0; j < 4; j++) {
        int n = nodeBase + ng + 8 * j;
        if (n < NN) {
            ushort4 o;
            o.x = f2h(acc[j].x); o.y = f2h(acc[j].y);
            o.z = f2h(acc[j].z); o.w = f2h(acc[j].w);
            ((ushort4*)(t0h + (size_t)n * HD))[fq] = o;
        }
    }
}

// ------- aggregate with dynamic work-stealing (4 pairs/chunk); pipelined gathers -------

__global__ __launch_bounds__(256) void k_agg(const ushort* __restrict__ t0h,
                                             const int2* __restrict__ srw,
                                             const int* __restrict__ startA,
                                             const int* __restrict__ deg,
                                             const float* __restrict__ dinv,
                                             const float* __restrict__ bias,
                                             int* __restrict__ ctr,
                                             float* __restrict__ agg,
                                             float* __restrict__ stats) {
    int t = threadIdx.x;
    int f = t & 127;
    int half = t >> 7;
    float bs = bias[f];
    float rs1 = 0.f, rs2 = 0.f;
    __shared__ int chunkS;
    for (;;) {
        __syncthreads();
        if (t == 0) chunkS = atomicAdd(ctr, 1);
        __syncthreads();
        int chunk = chunkS;
        if (chunk >= NCHUNK) break;
        int p0 = chunk * 4;
        for (int p = p0; p < p0 + 4; p++) {
            int i = p * 2 + half;                 // p < 25000 -> i < 50000 always
            int s = startA[i];
            int cnt = deg[i];                     // edge-only count
            int nb = (cnt + 7) & ~7;              // padded (sentinels w=0)
            int2 e[8];
            if (nb > 0) {
#pragma unroll
                for (int u = 0; u < 8; u++) e[u] = srw[s + u];
            }
            float di = dinv[i];
            float acc = di * di * h2f(t0h[i * HD + f]);   // self-loop term
            float a[8];
#pragma unroll
            for (int u = 0; u < 8; u++) a[u] = 0.f;
            for (int j = 0; j < nb; j += 8) {
                float g[8];
#pragma unroll
                for (int u = 0; u < 8; u++) g[u] = h2f(t0h[e[u].x + f]);   // gathers first
                int2 en[8];
                if (j + 8 < nb) {
#pragma unroll
                    for (int u = 0; u < 8; u++) en[u] = srw[s + j + 8 + u]; // prefetch next
                }
#pragma unroll
                for (int u = 0; u < 8; u++) a[u] += __int_as_float(e[u].y) * g[u];
                if (j + 8 < nb) {
#pragma unroll
                    for (int u = 0; u < 8; u++) e[u] = en[u];
                }
            }
            acc += ((a[0] + a[1]) + (a[2] + a[3])) + ((a[4] + a[5]) + (a[6] + a[7]));
            agg[(size_t)i * HD + f] = acc;
            float y = fmaxf(0.f, acc + bs);
            rs1 += y;
            rs2 += y * y;
        }
    }
    __shared__ float l1[256], l2[256];
    l1[t] = rs1; l2[t] = rs2;
    __syncthreads();
    if (t < 128) {
        atomicAdd(&stats[t], l1[t] + l1[t + 128]);
        atomicAdd(&stats[128 + t], l2[t] + l2[t + 128]);
    }
}

// ------- BN apply + residual + InstanceNorm (layer 2 only, in-place on h) -------

__global__ void k_post(const float* __restrict__ agg, const float* __restrict__ stats,
                       const float* __restrict__ bias, const float* __restrict__ bng,
                       const float* __restrict__ bnb, float* __restrict__ h) {
    int node = (blockIdx.x * 256 + threadIdx.x) >> 6;
    int lane = threadIdx.x & 63;
    if (node >= NN) return;
    const float invN = 1.f / NN;
    int f0 = lane, f1 = lane + 64;
    float m0 = stats[f0] * invN, m1 = stats[f1] * invN;
    float v0 = stats[128 + f0] * invN - m0 * m0;
    float v1 = stats[128 + f1] * invN - m1 * m1;
    float sc0 = bng[f0] * rsqrtf(v0 + EPSN);
    float sc1 = bng[f1] * rsqrtf(v1 + EPSN);
    float sh0 = bnb[f0] - m0 * sc0;
    float sh1 = bnb[f1] - m1 * sc1;
    size_t base = (size_t)node * HD;
    float y0 = fmaxf(0.f, agg[base + f0] + bias[f0]);
    float y1 = fmaxf(0.f, agg[base + f1] + bias[f1]);
    float u0 = y0 * sc0 + sh0 + h[base + f0];
    float u1 = y1 * sc1 + sh1 + h[base + f1];
    float s = u0 + u1, q = u0 * u0 + u1 * u1;
    for (int o = 32; o; o >>= 1) { s += __shfl_xor(s, o); q += __shfl_xor(q, o); }
    float m = s * (1.f / HD);
    float var = q * (1.f / HD) - m * m;
    float r = rsqrtf(var + EPSN);
    h[base + f0] = (u0 - m) * r;
    h[base + f1] = (u1 - m) * r;
}

// ------- head: relu(h @ fc1 + b) -> tanh(@ fc2 + b); output dtype per flag -------

__global__ __launch_bounds__(256) void k_head(const float* __restrict__ h,
                                              const float* __restrict__ cp,
                                              const int* __restrict__ flags,
                                              void* __restrict__ outv) {
    __shared__ float W1[HD * 32];   // 16 KB, flat [k][f]
    __shared__ float B1[32], W2[64], B2[2];
    int t = threadIdx.x;
    const float* f1W = cp + O_F1W;
    for (int r = 0; r < 16; r++) W1[r * 256 + t] = f1W[r * 256 + t];
    if (t < 32) B1[t] = cp[O_F1B + t];
    if (t < 64) W2[t] = cp[O_F2W + t];
    if (t < 2) B2[t] = cp[O_F2B + t];
    __syncthreads();
    int i = blockIdx.x * 256 + t;
    if (i >= NN) return;
    float a[32];
#pragma unroll
    for (int f = 0; f < 32; f++) a[f] = B1[f];
    const float4* hr = (const float4*)(h + (size_t)i * HD);
    for (int c = 0; c < 4; c++) {
        float hk[32];
#pragma unroll
        for (int qd = 0; qd < 8; qd++) {
            float4 v = hr[c * 8 + qd];
            hk[4 * qd] = v.x; hk[4 * qd + 1] = v.y; hk[4 * qd + 2] = v.z; hk[4 * qd + 3] = v.w;
        }
#pragma unroll
        for (int kk = 0; kk < 32; kk++) {
            float hv = hk[kk];
            const float4* wr = (const float4*)(W1 + (c * 32 + kk) * 32);
#pragma unroll
            for (int qd = 0; qd < 8; qd++) {
                float4 w = wr[qd];
                a[4 * qd] += hv * w.x; a[4 * qd + 1] += hv * w.y;
                a[4 * qd + 2] += hv * w.z; a[4 * qd + 3] += hv * w.w;
            }
        }
    }
    float o0 = B2[0], o1 = B2[1];
#pragma unroll
    for (int f = 0; f < 32; f++) {
        float av = fmaxf(0.f, a[f]);
        o0 += av * W2[f * 2];
        o1 += av * W2[f * 2 + 1];
    }
    o0 = tanhf(o0); o1 = tanhf(o1);
    if (flags[1]) {
        ushort* ob = (ushort*)outv;
        ob[i * 2] = f2us(o0);
        ob[i * 2 + 1] = f2us(o1);
    } else {
        float* of = (float*)outv;
        of[i * 2] = o0;
        of[i * 2 + 1] = o1;
    }
}

// ---------------- launch ----------------

extern "C" void kernel_launch(void* const* d_in, const int* in_sizes, int n_in,
                              void* d_out, int out_size, void* d_ws, size_t ws_size,
                              hipStream_t stream) {
    const int* ei = (const int*)d_in[1];

    Ptrs ptrs;
    ptrs.p[0] = d_in[0];                                  // x
    for (int s = 1; s < 17; s++) ptrs.p[s] = d_in[s + 1]; // coord_W .. fc2_b

    char* wsp = (char*)d_ws;
    size_t off = 0;
    auto alloc = [&](size_t bytes) {
        void* p = wsp + off;
        off += (bytes + 255) & ~(size_t)255;
        return p;
    };
    float* cp     = (float*)alloc((size_t)O_TOT * 4);       // 0.62 MB canonical fp32 params
    float* h      = (float*)alloc((size_t)NN * HD * 4);     // 25.6 MB
    ushort* t0h   = (ushort*)alloc((size_t)NN * HD * 2);    // 12.8 MB fp16
    float* agg    = (float*)alloc((size_t)NN * HD * 4);     // 25.6 MB
    int* zr       = (int*)alloc((size_t)(NN + 768 + 64) * 4); // zeroed region
    float* dinv   = (float*)alloc((size_t)NN * 4);
    int2* srw     = (int2*)alloc((size_t)CAP * 8);          // 9.2 MB padded CSR
    int* startA   = (int*)alloc((size_t)NN * 4);
    int* curA     = (int*)alloc((size_t)NN * 4);

    int* deg     = zr;                      // NN ints
    float* stats = (float*)(zr + NN);       // 768 floats (3 layers x 256)
    int* misc    = zr + NN + 768;           // [0]=alloc cursor, [1..3]=steal ctrs, [8..9]=flags
    int* flags   = misc + 8;

    const int BN_NODE = (NN + 255) / 256;   // 196
    const int BN_EDGE = (NE + 255) / 256;   // 3125
    const int BN_CONV = (O_TOT + 255) / 256;

    const float* W[3] = {cp + O_W1, cp + O_W2, cp + O_W3};
    const float* B[3] = {cp + O_B1, cp + O_B2, cp + O_B3};

    hipMemsetAsync(zr, 0, (size_t)(NN + 768 + 64) * 4, stream);
    k_conv<<<BN_CONV, 256, 0, stream>>>(ptrs, ei, (const ushort*)d_in[2], cp, flags);
    k_deg<<<BN_EDGE, 256, 0, stream>>>(ei, flags, deg);
    k_dinv_alloc<<<BN_NODE, 256, 0, stream>>>(deg, dinv, startA, curA, misc, srw);
    k_fill<<<BN_EDGE, 256, 0, stream>>>(ei, flags, dinv, curA, srw);

    k_gemm0<<<(NN + 31) / 32, 256, 0, stream>>>(cp, h, W[0], t0h);
    k_agg<<<2048, 256, 0, stream>>>(t0h, srw, startA, deg, dinv, B[0], misc + 1,
                                    agg, stats);
    for (int l = 1; l < 3; l++) {
        k_gemm_fused<<<(NN + 31) / 32, 256, 0, stream>>>(agg, stats + 256 * (l - 1),
                                                         B[l - 1], cp + O_BNG, cp + O_BNB,
                                                         h, W[l], t0h);
        k_agg<<<2048, 256, 0, stream>>>(t0h, srw, startA, deg, dinv, B[l], misc + 1 + l,
                                        agg, stats + 256 * l);
    }
    k_post<<<NN / 4, 256, 0, stream>>>(agg, stats + 512, B[2], cp + O_BNG, cp + O_BNB, h);
    k_head<<<BN_NODE, 256, 0, stream>>>(h, cp, flags, d_out);
}

// Round 11
// 685.061 us; speedup vs baseline: 1.1985x; 1.1985x over previous
//
#include <hip/hip_runtime.h>
#include <hip/hip_bf16.h>
#include <hip/hip_fp16.h>
#include <stdint.h>

#define NN 50000
#define NE 800000
#define HD 128
#define EPSN 1e-5f
#define CAP 1152000   // padded CSR capacity: NE + NN*7 rounded up

typedef __hip_bfloat16 bf16;

__device__ __forceinline__ float us2f(unsigned short u) { return __uint_as_float((uint32_t)u << 16); }
__device__ __forceinline__ ushort f2us(float f) {
    bf16 b = __float2bfloat16(f);
    return *reinterpret_cast<ushort*>(&b);
}
__device__ __forceinline__ ushort f2h(float f) {
    __half h = __float2half(f);
    return *reinterpret_cast<ushort*>(&h);
}
__device__ __forceinline__ float h2f(ushort u) {
    __half h = *reinterpret_cast<__half*>(&u);
    return __half2float(h);
}

// canonical fp32 parameter block offsets
#define O_X    0
#define O_CW   100000
#define O_CB   100256
#define O_LNG  100384
#define O_LNB  100512
#define O_BNG  100640
#define O_BNB  100768
#define O_W1   100896
#define O_B1   117280
#define O_W2   117408
#define O_B2   133792
#define O_W3   133920
#define O_B3   150304
#define O_F1W  150432
#define O_F1B  154528
#define O_F2W  154560
#define O_F2B  154624
#define O_TOT  154626

struct Ptrs { const void* p[17]; };

__device__ const int SEG_OFF[18] = {O_X, O_CW, O_CB, O_LNG, O_LNB, O_BNG, O_BNB,
                                    O_W1, O_B1, O_W2, O_B2, O_W3, O_B3,
                                    O_F1W, O_F1B, O_F2W, O_F2B, O_TOT};

// Edge accessor: isL=1 -> int64 storage (read low words), else int32.
__device__ __forceinline__ int eidx(const int* __restrict__ ei, int isL, int which, int e) {
    size_t base = (size_t)which * NE + e;
    return isL ? ei[2 * base] : ei[base];
}

// ------- canonicalize floats to fp32; self-detects bf16; block 0 publishes flags -------
__global__ void k_conv(Ptrs ptrs, const int* __restrict__ ei, const ushort* __restrict__ cw,
                       float* __restrict__ cp, int* __restrict__ flags) {
    int t = threadIdx.x;
    __shared__ int sb[4], sv[4];
    int bad = 0;
    if (t < 128) {
        float val = us2f(cw[2 * t]);           // low half if f32, real weight if bf16
        bad = !(fabsf(val) <= 1.0f);           // NaN/Inf -> bad
    }
    for (int o = 32; o; o >>= 1) bad |= __shfl_xor(bad, o);
    if ((t & 63) == 0) sb[t >> 6] = bad;
    __syncthreads();
    int isB = ((sb[0] | sb[1] | sb[2] | sb[3]) == 0) ? 1 : 0;
    if (blockIdx.x == 0) {
        int v = ei[2 * t + 1] | ei[1000000 + 2 * t + 1];   // int64 -> odd words all zero
        for (int o = 32; o; o >>= 1) v |= __shfl_xor(v, o);
        if ((t & 63) == 0) sv[t >> 6] = v;
        __syncthreads();
        if (t == 0) {
            flags[0] = ((sv[0] | sv[1] | sv[2] | sv[3]) == 0) ? 1 : 0;
            flags[1] = isB;
        }
    }
    int i = blockIdx.x * 256 + t;
    if (i >= O_TOT) return;
    int s = 0;
    while (i >= SEG_OFF[s + 1]) s++;
    int local = i - SEG_OFF[s];
    const void* src = ptrs.p[s];
    cp[i] = isB ? us2f(((const ushort*)src)[local]) : ((const float*)src)[local];
}

// ---------------- graph preprocessing (deg zeroed by memset; = edge-only count) ------

__global__ void k_deg(const int* __restrict__ ei, const int* __restrict__ flags,
                      int* __restrict__ deg) {
    int e = blockIdx.x * 256 + threadIdx.x;
    if (e < NE) atomicAdd(&deg[eidx(ei, flags[0], 1, e)], 1);
}

__global__ void k_dinv_alloc(const int* __restrict__ deg, float* __restrict__ dinv,
                             int* __restrict__ startA, int* __restrict__ curA,
                             int* __restrict__ cursor, int2* __restrict__ srw) {
    int i = blockIdx.x * 256 + threadIdx.x;
    if (i < NN) {
        int c = deg[i];                        // edge-only in-count
        dinv[i] = rsqrtf((float)(c + 1));      // +1 self-loop
        int cpad = (c + 7) & ~7;               // pad list to multiple of 8
        int s = atomicAdd(cursor, cpad);
        startA[i] = s;
        curA[i] = s;
        for (int j = c; j < cpad; j++) srw[s + j] = make_int2(0, 0);  // sentinels w=0
    }
}

__global__ void k_fill(const int* __restrict__ ei, const int* __restrict__ flags,
                       const float* __restrict__ dinv, int* __restrict__ curA,
                       int2* __restrict__ srw) {
    int e = blockIdx.x * 256 + threadIdx.x;
    if (e >= NE) return;
    int isL = flags[0];
    int r = eidx(ei, isL, 0, e);
    int c = eidx(ei, isL, 1, e);
    int p = atomicAdd(&curA[c], 1);
    srw[p] = make_int2(r << 7, __float_as_int(dinv[r] * dinv[c]));
}

// ------- layer-0 GEMM fused with embed: u = LN(relu(x@cW+cb)); h=u; t0h=fp16(u@W) -------

__global__ __launch_bounds__(256) void k_gemm0(const float* __restrict__ cp,
                                               float* __restrict__ h,
                                               const float* __restrict__ Wf,
                                               ushort* __restrict__ t0h) {
    __shared__ float Wl[64 * HD];       // 32 KB
    __shared__ float hl[32 * HD];       // 16 KB
    __shared__ float sCW[2 * HD], sCB[HD], sLG[HD], sLB[HD];
    int t = threadIdx.x;
    sCW[t] = cp[O_CW + t];
    if (t < 128) { sCB[t] = cp[O_CB + t]; sLG[t] = cp[O_LNG + t]; sLB[t] = cp[O_LNB + t]; }
    __syncthreads();
    int nodeBase = blockIdx.x * 32;
    const float* X = cp + O_X;
    float4* h4g = (float4*)h;
    float4* hl4 = (float4*)hl;
#pragma unroll
    for (int r = 0; r < 4; r++) {
        int idx = r * 256 + t;
        int n = nodeBase + (idx >> 5);
        int c4 = idx & 31;
        int f = c4 * 4;
        float4 u = make_float4(0.f, 0.f, 0.f, 0.f);
        if (n < NN) {
            float x0 = X[n * 2], x1 = X[n * 2 + 1];
            u.x = fmaxf(0.f, x0 * sCW[f]     + x1 * sCW[HD + f]     + sCB[f]);
            u.y = fmaxf(0.f, x0 * sCW[f + 1] + x1 * sCW[HD + f + 1] + sCB[f + 1]);
            u.z = fmaxf(0.f, x0 * sCW[f + 2] + x1 * sCW[HD + f + 2] + sCB[f + 2]);
            u.w = fmaxf(0.f, x0 * sCW[f + 3] + x1 * sCW[HD + f + 3] + sCB[f + 3]);
        }
        float s = u.x + u.y + u.z + u.w;
        float q = u.x * u.x + u.y * u.y + u.z * u.z + u.w * u.w;
        for (int o = 16; o; o >>= 1) { s += __shfl_xor(s, o); q += __shfl_xor(q, o); }
        float m = s * (1.f / HD);
        float var = q * (1.f / HD) - m * m;
        float rr = rsqrtf(var + EPSN);
        u.x = (u.x - m) * rr * sLG[f]     + sLB[f];
        u.y = (u.y - m) * rr * sLG[f + 1] + sLB[f + 1];
        u.z = (u.z - m) * rr * sLG[f + 2] + sLB[f + 2];
        u.w = (u.w - m) * rr * sLG[f + 3] + sLB[f + 3];
        hl4[idx] = u;
        if (n < NN) h4g[(size_t)n * 32 + c4] = u;
    }
    int fq = t & 31;
    int ng = t >> 5;
    float4 acc[4];
#pragma unroll
    for (int j = 0; j < 4; j++) acc[j] = make_float4(0.f, 0.f, 0.f, 0.f);
    const float4* Wl4 = (const float4*)Wl;
    for (int ph = 0; ph < 2; ph++) {
        __syncthreads();
        const float4* Wg4 = (const float4*)(Wf + ph * 64 * HD);
        float4* Wld = (float4*)Wl;
#pragma unroll
        for (int r = 0; r < 8; r++) Wld[r * 256 + t] = Wg4[r * 256 + t];
        __syncthreads();
        for (int k4 = 0; k4 < 16; k4++) {
            int kb = k4 * 4;
            float4 w0 = Wl4[(kb + 0) * 32 + fq];
            float4 w1 = Wl4[(kb + 1) * 32 + fq];
            float4 w2 = Wl4[(kb + 2) * 32 + fq];
            float4 w3 = Wl4[(kb + 3) * 32 + fq];
#pragma unroll
            for (int j = 0; j < 4; j++) {
                float4 hv = hl4[(ng + 8 * j) * 32 + ph * 16 + k4];
                acc[j].x += hv.x * w0.x + hv.y * w1.x + hv.z * w2.x + hv.w * w3.x;
                acc[j].y += hv.x * w0.y + hv.y * w1.y + hv.z * w2.y + hv.w * w3.y;
                acc[j].z += hv.x * w0.z + hv.y * w1.z + hv.z * w2.z + hv.w * w3.z;
                acc[j].w += hv.x * w0.w + hv.y * w1.w + hv.z * w2.w + hv.w * w3.w;
            }
        }
    }
#pragma unroll
    for (int j = 0; j < 4; j++) {
        int n = nodeBase + ng + 8 * j;
        if (n < NN) {
            ushort4 o;
            o.x = f2h(acc[j].x); o.y = f2h(acc[j].y);
            o.z = f2h(acc[j].z); o.w = f2h(acc[j].w);
            ((ushort4*)(t0h + (size_t)n * HD))[fq] = o;
        }
    }
}

// ------- fused BN+residual+InstanceNorm + GEMM (layers 1,2) -------

__global__ __launch_bounds__(256) void k_gemm_fused(const float* __restrict__ agg,
                                                    const float* __restrict__ stats,
                                                    const float* __restrict__ bias,
                                                    const float* __restrict__ bng,
                                                    const float* __restrict__ bnb,
                                                    float* __restrict__ h,
                                                    const float* __restrict__ Wf,
                                                    ushort* __restrict__ t0h) {
    __shared__ float Wl[64 * HD];       // 32 KB
    __shared__ float hl[32 * HD];       // 16 KB
    __shared__ float scL[HD], shL[HD], bL[HD];
    int t = threadIdx.x;
    if (t < 128) {
        const float invN = 1.f / NN;
        float m = stats[t] * invN;
        float v = stats[128 + t] * invN - m * m;
        float sc = bng[t] * rsqrtf(v + EPSN);
        scL[t] = sc;
        shL[t] = bnb[t] - m * sc;
        bL[t] = bias[t];
    }
    __syncthreads();
    int nodeBase = blockIdx.x * 32;
    const float4* a4 = (const float4*)agg;
    float4* h4g = (float4*)h;
    float4* hl4 = (float4*)hl;
#pragma unroll
    for (int r = 0; r < 4; r++) {
        int idx = r * 256 + t;
        int n = nodeBase + (idx >> 5);
        int c4 = idx & 31;
        float4 u = make_float4(0.f, 0.f, 0.f, 0.f);
        if (n < NN) {
            float4 av = a4[(size_t)n * 32 + c4];
            float4 hv = h4g[(size_t)n * 32 + c4];
            int f = c4 * 4;
            float y0 = fmaxf(0.f, av.x + bL[f]);
            float y1 = fmaxf(0.f, av.y + bL[f + 1]);
            float y2 = fmaxf(0.f, av.z + bL[f + 2]);
            float y3 = fmaxf(0.f, av.w + bL[f + 3]);
            u.x = y0 * scL[f]     + shL[f]     + hv.x;
            u.y = y1 * scL[f + 1] + shL[f + 1] + hv.y;
            u.z = y2 * scL[f + 2] + shL[f + 2] + hv.z;
            u.w = y3 * scL[f + 3] + shL[f + 3] + hv.w;
        }
        float s = u.x + u.y + u.z + u.w;
        float q = u.x * u.x + u.y * u.y + u.z * u.z + u.w * u.w;
        for (int o = 16; o; o >>= 1) { s += __shfl_xor(s, o); q += __shfl_xor(q, o); }
        float m = s * (1.f / HD);
        float var = q * (1.f / HD) - m * m;
        float rr = rsqrtf(var + EPSN);
        u.x = (u.x - m) * rr; u.y = (u.y - m) * rr;
        u.z = (u.z - m) * rr; u.w = (u.w - m) * rr;
        hl4[idx] = u;
        if (n < NN) h4g[(size_t)n * 32 + c4] = u;
    }
    int fq = t & 31;
    int ng = t >> 5;
    float4 acc[4];
#pragma unroll
    for (int j = 0; j < 4; j++) acc[j] = make_float4(0.f, 0.f, 0.f, 0.f);
    const float4* Wl4 = (const float4*)Wl;
    for (int ph = 0; ph < 2; ph++) {
        __syncthreads();
        const float4* Wg4 = (const float4*)(Wf + ph * 64 * HD);
        float4* Wld = (float4*)Wl;
#pragma unroll
        for (int r = 0; r < 8; r++) Wld[r * 256 + t] = Wg4[r * 256 + t];
        __syncthreads();
        for (int k4 = 0; k4 < 16; k4++) {
            int kb = k4 * 4;
            float4 w0 = Wl4[(kb + 0) * 32 + fq];
            float4 w1 = Wl4[(kb + 1) * 32 + fq];
            float4 w2 = Wl4[(kb + 2) * 32 + fq];
            float4 w3 = Wl4[(kb + 3) * 32 + fq];
#pragma unroll
            for (int j = 0; j < 4; j++) {
                float4 hv = hl4[(ng + 8 * j) * 32 + ph * 16 + k4];
                acc[j].x += hv.x * w0.x + hv.y * w1.x + hv.z * w2.x + hv.w * w3.x;
                acc[j].y += hv.x * w0.y + hv.y * w1.y + hv.z * w2.y + hv.w * w3.y;
                acc[j].z += hv.x * w0.z + hv.y * w1.z + hv.z * w2.z + hv.w * w3.z;
                acc[j].w += hv.x * w0.w + hv.y * w1.w + hv.z * w2.w + hv.w * w3.w;
            }
        }
    }
#pragma unroll
    for (int j = 0; j < 4; j++) {
        int n = nodeBase + ng + 8 * j;
        if (n < NN) {
            ushort4 o;
            o.x = f2h(acc[j].x); o.y = f2h(acc[j].y);
            o.z = f2h(acc[j].z); o.w = f2h(acc[j].w);
            ((ushort4*)(t0h + (size_t)n * HD))[fq] = o;
        }
    }
}

// ------- aggregate (round-9 structure): static grid-stride, barrier-free main loop,
// padded tail-free CSR, software-pipelined gathers (FIFO vmcnt keeps prefetch live) -------

__global__ __launch_bounds__(256) void k_agg(const ushort* __restrict__ t0h,
                                             const int2* __restrict__ srw,
                                             const int* __restrict__ startA,
                                             const int* __restrict__ deg,
                                             const float* __restrict__ dinv,
                                             const float* __restrict__ bias,
                                             float* __restrict__ agg,
                                             float* __restrict__ stats) {
    int t = threadIdx.x;
    int f = t & 127;
    int half = t >> 7;
    float bs = bias[f];
    float rs1 = 0.f, rs2 = 0.f;
    for (int pair = blockIdx.x; pair * 2 < NN; pair += gridDim.x) {
        int i = pair * 2 + half;
        if (i < NN) {
            int s = startA[i];
            int cnt = deg[i];                 // edge-only count
            int nb = (cnt + 7) & ~7;          // padded batch count (sentinels w=0)
            int2 e[8];
            if (nb > 0) {
#pragma unroll
                for (int u = 0; u < 8; u++) e[u] = srw[s + u];
            }
            float di = dinv[i];
            float acc = di * di * h2f(t0h[i * HD + f]);   // self-loop term
            float a[8];
#pragma unroll
            for (int u = 0; u < 8; u++) a[u] = 0.f;
            for (int j = 0; j < nb; j += 8) {
                float g[8];
#pragma unroll
                for (int u = 0; u < 8; u++) g[u] = h2f(t0h[e[u].x + f]);   // gathers first
                int2 en[8];
                if (j + 8 < nb) {
#pragma unroll
                    for (int u = 0; u < 8; u++) en[u] = srw[s + j + 8 + u]; // prefetch next
                }
#pragma unroll
                for (int u = 0; u < 8; u++) a[u] += __int_as_float(e[u].y) * g[u];
                if (j + 8 < nb) {
#pragma unroll
                    for (int u = 0; u < 8; u++) e[u] = en[u];
                }
            }
            acc += ((a[0] + a[1]) + (a[2] + a[3])) + ((a[4] + a[5]) + (a[6] + a[7]));
            agg[(size_t)i * HD + f] = acc;
            float y = fmaxf(0.f, acc + bs);
            rs1 += y;
            rs2 += y * y;
        }
    }
    __shared__ float l1[256], l2[256];
    l1[t] = rs1; l2[t] = rs2;
    __syncthreads();
    if (t < 128) {
        atomicAdd(&stats[t], l1[t] + l1[t + 128]);
        atomicAdd(&stats[128 + t], l2[t] + l2[t + 128]);
    }
}

// ------- BN apply + residual + InstanceNorm (layer 2 only, in-place on h) -------

__global__ void k_post(const float* __restrict__ agg, const float* __restrict__ stats,
                       const float* __restrict__ bias, const float* __restrict__ bng,
                       const float* __restrict__ bnb, float* __restrict__ h) {
    int node = (blockIdx.x * 256 + threadIdx.x) >> 6;
    int lane = threadIdx.x & 63;
    if (node >= NN) return;
    const float invN = 1.f / NN;
    int f0 = lane, f1 = lane + 64;
    float m0 = stats[f0] * invN, m1 = stats[f1] * invN;
    float v0 = stats[128 + f0] * invN - m0 * m0;
    float v1 = stats[128 + f1] * invN - m1 * m1;
    float sc0 = bng[f0] * rsqrtf(v0 + EPSN);
    float sc1 = bng[f1] * rsqrtf(v1 + EPSN);
    float sh0 = bnb[f0] - m0 * sc0;
    float sh1 = bnb[f1] - m1 * sc1;
    size_t base = (size_t)node * HD;
    float y0 = fmaxf(0.f, agg[base + f0] + bias[f0]);
    float y1 = fmaxf(0.f, agg[base + f1] + bias[f1]);
    float u0 = y0 * sc0 + sh0 + h[base + f0];
    float u1 = y1 * sc1 + sh1 + h[base + f1];
    float s = u0 + u1, q = u0 * u0 + u1 * u1;
    for (int o = 32; o; o >>= 1) { s += __shfl_xor(s, o); q += __shfl_xor(q, o); }
    float m = s * (1.f / HD);
    float var = q * (1.f / HD) - m * m;
    float r = rsqrtf(var + EPSN);
    h[base + f0] = (u0 - m) * r;
    h[base + f1] = (u1 - m) * r;
}

// ------- head: relu(h @ fc1 + b) -> tanh(@ fc2 + b); output dtype per flag -------

__global__ __launch_bounds__(256) void k_head(const float* __restrict__ h,
                                              const float* __restrict__ cp,
                                              const int* __restrict__ flags,
                                              void* __restrict__ outv) {
    __shared__ float W1[HD * 32];   // 16 KB, flat [k][f]
    __shared__ float B1[32], W2[64], B2[2];
    int t = threadIdx.x;
    const float* f1W = cp + O_F1W;
    for (int r = 0; r < 16; r++) W1[r * 256 + t] = f1W[r * 256 + t];
    if (t < 32) B1[t] = cp[O_F1B + t];
    if (t < 64) W2[t] = cp[O_F2W + t];
    if (t < 2) B2[t] = cp[O_F2B + t];
    __syncthreads();
    int i = blockIdx.x * 256 + t;
    if (i >= NN) return;
    float a[32];
#pragma unroll
    for (int f = 0; f < 32; f++) a[f] = B1[f];
    const float4* hr = (const float4*)(h + (size_t)i * HD);
    for (int c = 0; c < 4; c++) {
        float hk[32];
#pragma unroll
        for (int qd = 0; qd < 8; qd++) {
            float4 v = hr[c * 8 + qd];
            hk[4 * qd] = v.x; hk[4 * qd + 1] = v.y; hk[4 * qd + 2] = v.z; hk[4 * qd + 3] = v.w;
        }
#pragma unroll
        for (int kk = 0; kk < 32; kk++) {
            float hv = hk[kk];
            const float4* wr = (const float4*)(W1 + (c * 32 + kk) * 32);
#pragma unroll
            for (int qd = 0; qd < 8; qd++) {
                float4 w = wr[qd];
                a[4 * qd] += hv * w.x; a[4 * qd + 1] += hv * w.y;
                a[4 * qd + 2] += hv * w.z; a[4 * qd + 3] += hv * w.w;
            }
        }
    }
    float o0 = B2[0], o1 = B2[1];
#pragma unroll
    for (int f = 0; f < 32; f++) {
        float av = fmaxf(0.f, a[f]);
        o0 += av * W2[f * 2];
        o1 += av * W2[f * 2 + 1];
    }
    o0 = tanhf(o0); o1 = tanhf(o1);
    if (flags[1]) {
        ushort* ob = (ushort*)outv;
        ob[i * 2] = f2us(o0);
        ob[i * 2 + 1] = f2us(o1);
    } else {
        float* of = (float*)outv;
        of[i * 2] = o0;
        of[i * 2 + 1] = o1;
    }
}

// ---------------- launch ----------------

extern "C" void kernel_launch(void* const* d_in, const int* in_sizes, int n_in,
                              void* d_out, int out_size, void* d_ws, size_t ws_size,
                              hipStream_t stream) {
    const int* ei = (const int*)d_in[1];

    Ptrs ptrs;
    ptrs.p[0] = d_in[0];                                  // x
    for (int s = 1; s < 17; s++) ptrs.p[s] = d_in[s + 1]; // coord_W .. fc2_b

    char* wsp = (char*)d_ws;
    size_t off = 0;
    auto alloc = [&](size_t bytes) {
        void* p = wsp + off;
        off += (bytes + 255) & ~(size_t)255;
        return p;
    };
    float* cp     = (float*)alloc((size_t)O_TOT * 4);       // 0.62 MB canonical fp32 params
    float* h      = (float*)alloc((size_t)NN * HD * 4);     // 25.6 MB
    ushort* t0h   = (ushort*)alloc((size_t)NN * HD * 2);    // 12.8 MB fp16
    float* agg    = (float*)alloc((size_t)NN * HD * 4);     // 25.6 MB
    int* zr       = (int*)alloc((size_t)(NN + 768 + 64) * 4); // zeroed region
    float* dinv   = (float*)alloc((size_t)NN * 4);
    int2* srw     = (int2*)alloc((size_t)CAP * 8);          // 9.2 MB padded CSR
    int* startA   = (int*)alloc((size_t)NN * 4);
    int* curA     = (int*)alloc((size_t)NN * 4);

    int* deg     = zr;                      // NN ints (edge-only in-degree)
    float* stats = (float*)(zr + NN);       // 768 floats (3 layers x 256)
    int* misc    = zr + NN + 768;           // [0]=alloc cursor, [8..9]=flags
    int* flags   = misc + 8;

    const int BN_NODE = (NN + 255) / 256;   // 196
    const int BN_EDGE = (NE + 255) / 256;   // 3125
    const int BN_CONV = (O_TOT + 255) / 256;

    const float* W[3] = {cp + O_W1, cp + O_W2, cp + O_W3};
    const float* B[3] = {cp + O_B1, cp + O_B2, cp + O_B3};

    hipMemsetAsync(zr, 0, (size_t)(NN + 768 + 64) * 4, stream);
    k_conv<<<BN_CONV, 256, 0, stream>>>(ptrs, ei, (const ushort*)d_in[2], cp, flags);
    k_deg<<<BN_EDGE, 256, 0, stream>>>(ei, flags, deg);
    k_dinv_alloc<<<BN_NODE, 256, 0, stream>>>(deg, dinv, startA, curA, misc, srw);
    k_fill<<<BN_EDGE, 256, 0, stream>>>(ei, flags, dinv, curA, srw);

    k_gemm0<<<(NN + 31) / 32, 256, 0, stream>>>(cp, h, W[0], t0h);
    k_agg<<<2048, 256, 0, stream>>>(t0h, srw, startA, deg, dinv, B[0], agg, stats);
    for (int l = 1; l < 3; l++) {
        k_gemm_fused<<<(NN + 31) / 32, 256, 0, stream>>>(agg, stats + 256 * (l - 1),
                                                         B[l - 1], cp + O_BNG, cp + O_BNB,
                                                         h, W[l], t0h);
        k_agg<<<2048, 256, 0, stream>>>(t0h, srw, startA, deg, dinv, B[l],
                                        agg, stats + 256 * l);
    }
    k_post<<<NN / 4, 256, 0, stream>>>(agg, stats + 512, B[2], cp + O_BNG, cp + O_BNB, h);
    k_head<<<BN_NODE, 256, 0, stream>>>(h, cp, flags, d_out);
}

// Round 12
// 677.618 us; speedup vs baseline: 1.2116x; 1.0110x over previous
//
#include <hip/hip_runtime.h>
#include <hip/hip_bf16.h>
#include <hip/hip_fp16.h>
#include <stdint.h>

#define NN 50000
#define NE 800000
#define HD 128
#define EPSN 1e-5f
#define CAP 1152000   // padded CSR capacity: NE + NN*7 rounded up

typedef __hip_bfloat16 bf16;

__device__ __forceinline__ float us2f(unsigned short u) { return __uint_as_float((uint32_t)u << 16); }
__device__ __forceinline__ ushort f2us(float f) {
    bf16 b = __float2bfloat16(f);
    return *reinterpret_cast<ushort*>(&b);
}
__device__ __forceinline__ ushort f2h(float f) {
    __half h = __float2half(f);
    return *reinterpret_cast<ushort*>(&h);
}
__device__ __forceinline__ float h2f(ushort u) {
    __half h = *reinterpret_cast<__half*>(&u);
    return __half2float(h);
}

// canonical fp32 parameter block offsets
#define O_X    0
#define O_CW   100000
#define O_CB   100256
#define O_LNG  100384
#define O_LNB  100512
#define O_BNG  100640
#define O_BNB  100768
#define O_W1   100896
#define O_B1   117280
#define O_W2   117408
#define O_B2   133792
#define O_W3   133920
#define O_B3   150304
#define O_F1W  150432
#define O_F1B  154528
#define O_F2W  154560
#define O_F2B  154624
#define O_TOT  154626

struct Ptrs { const void* p[17]; };

__device__ const int SEG_OFF[18] = {O_X, O_CW, O_CB, O_LNG, O_LNB, O_BNG, O_BNB,
                                    O_W1, O_B1, O_W2, O_B2, O_W3, O_B3,
                                    O_F1W, O_F1B, O_F2W, O_F2B, O_TOT};

// Edge accessor: isL=1 -> int64 storage (read low words), else int32.
__device__ __forceinline__ int eidx(const int* __restrict__ ei, int isL, int which, int e) {
    size_t base = (size_t)which * NE + e;
    return isL ? ei[2 * base] : ei[base];
}

// ------- canonicalize floats to fp32; self-detects bf16; block 0 publishes flags -------
__global__ void k_conv(Ptrs ptrs, const int* __restrict__ ei, const ushort* __restrict__ cw,
                       float* __restrict__ cp, int* __restrict__ flags) {
    int t = threadIdx.x;
    __shared__ int sb[4], sv[4];
    int bad = 0;
    if (t < 128) {
        float val = us2f(cw[2 * t]);           // low half if f32, real weight if bf16
        bad = !(fabsf(val) <= 1.0f);           // NaN/Inf -> bad
    }
    for (int o = 32; o; o >>= 1) bad |= __shfl_xor(bad, o);
    if ((t & 63) == 0) sb[t >> 6] = bad;
    __syncthreads();
    int isB = ((sb[0] | sb[1] | sb[2] | sb[3]) == 0) ? 1 : 0;
    if (blockIdx.x == 0) {
        int v = ei[2 * t + 1] | ei[1000000 + 2 * t + 1];   // int64 -> odd words all zero
        for (int o = 32; o; o >>= 1) v |= __shfl_xor(v, o);
        if ((t & 63) == 0) sv[t >> 6] = v;
        __syncthreads();
        if (t == 0) {
            flags[0] = ((sv[0] | sv[1] | sv[2] | sv[3]) == 0) ? 1 : 0;
            flags[1] = isB;
        }
    }
    int i = blockIdx.x * 256 + t;
    if (i >= O_TOT) return;
    int s = 0;
    while (i >= SEG_OFF[s + 1]) s++;
    int local = i - SEG_OFF[s];
    const void* src = ptrs.p[s];
    cp[i] = isB ? us2f(((const ushort*)src)[local]) : ((const float*)src)[local];
}

// ---------------- graph preprocessing (deg zeroed by memset; = edge-only count) ------

__global__ void k_deg(const int* __restrict__ ei, const int* __restrict__ flags,
                      int* __restrict__ deg) {
    int e = blockIdx.x * 256 + threadIdx.x;
    if (e < NE) atomicAdd(&deg[eidx(ei, flags[0], 1, e)], 1);
}

// wave-aggregated cursor: shfl prefix-scan of cpad, ONE atomic per wave (781 total,
// vs 50000 same-address atomics which serialize at the L2 bank).
__global__ void k_dinv_alloc(const int* __restrict__ deg, float* __restrict__ dinv,
                             int* __restrict__ startA, int* __restrict__ curA,
                             int* __restrict__ cursor, int2* __restrict__ srw) {
    int i = blockIdx.x * 256 + threadIdx.x;
    int lane = threadIdx.x & 63;
    int c = 0, cpad = 0;
    bool valid = (i < NN);
    if (valid) {
        c = deg[i];                        // edge-only in-count
        dinv[i] = rsqrtf((float)(c + 1));  // +1 self-loop
        cpad = (c + 7) & ~7;               // pad list to multiple of 8
    }
    int scan = cpad;                       // inclusive wave scan
    for (int o = 1; o < 64; o <<= 1) {
        int v = __shfl_up(scan, o);
        if (lane >= o) scan += v;
    }
    int tot = __shfl(scan, 63);
    int base = 0;
    if (lane == 0) base = atomicAdd(cursor, tot);
    base = __shfl(base, 0);
    int s = base + scan - cpad;            // exclusive offset
    if (valid) {
        startA[i] = s;
        curA[i] = s;
        for (int j = c; j < cpad; j++) srw[s + j] = make_int2(0, 0);  // sentinels w=0
    }
}

__global__ void k_fill(const int* __restrict__ ei, const int* __restrict__ flags,
                       const float* __restrict__ dinv, int* __restrict__ curA,
                       int2* __restrict__ srw) {
    int e = blockIdx.x * 256 + threadIdx.x;
    if (e >= NE) return;
    int isL = flags[0];
    int r = eidx(ei, isL, 0, e);
    int c = eidx(ei, isL, 1, e);
    int p = atomicAdd(&curA[c], 1);
    srw[p] = make_int2(r << 7, __float_as_int(dinv[r] * dinv[c]));
}

// ------- layer-0 GEMM fused with embed: u = LN(relu(x@cW+cb)); h=u; t0h=fp16(u@W) -------

__global__ __launch_bounds__(256) void k_gemm0(const float* __restrict__ cp,
                                               float* __restrict__ h,
                                               const float* __restrict__ Wf,
                                               ushort* __restrict__ t0h) {
    __shared__ float Wl[64 * HD];       // 32 KB
    __shared__ float hl[32 * HD];       // 16 KB
    __shared__ float sCW[2 * HD], sCB[HD], sLG[HD], sLB[HD];
    int t = threadIdx.x;
    sCW[t] = cp[O_CW + t];
    if (t < 128) { sCB[t] = cp[O_CB + t]; sLG[t] = cp[O_LNG + t]; sLB[t] = cp[O_LNB + t]; }
    __syncthreads();
    int nodeBase = blockIdx.x * 32;
    const float* X = cp + O_X;
    float4* h4g = (float4*)h;
    float4* hl4 = (float4*)hl;
#pragma unroll
    for (int r = 0; r < 4; r++) {
        int idx = r * 256 + t;
        int n = nodeBase + (idx >> 5);
        int c4 = idx & 31;
        int f = c4 * 4;
        float4 u = make_float4(0.f, 0.f, 0.f, 0.f);
        if (n < NN) {
            float x0 = X[n * 2], x1 = X[n * 2 + 1];
            u.x = fmaxf(0.f, x0 * sCW[f]     + x1 * sCW[HD + f]     + sCB[f]);
            u.y = fmaxf(0.f, x0 * sCW[f + 1] + x1 * sCW[HD + f + 1] + sCB[f + 1]);
            u.z = fmaxf(0.f, x0 * sCW[f + 2] + x1 * sCW[HD + f + 2] + sCB[f + 2]);
            u.w = fmaxf(0.f, x0 * sCW[f + 3] + x1 * sCW[HD + f + 3] + sCB[f + 3]);
        }
        float s = u.x + u.y + u.z + u.w;
        float q = u.x * u.x + u.y * u.y + u.z * u.z + u.w * u.w;
        for (int o = 16; o; o >>= 1) { s += __shfl_xor(s, o); q += __shfl_xor(q, o); }
        float m = s * (1.f / HD);
        float var = q * (1.f / HD) - m * m;
        float rr = rsqrtf(var + EPSN);
        u.x = (u.x - m) * rr * sLG[f]     + sLB[f];
        u.y = (u.y - m) * rr * sLG[f + 1] + sLB[f + 1];
        u.z = (u.z - m) * rr * sLG[f + 2] + sLB[f + 2];
        u.w = (u.w - m) * rr * sLG[f + 3] + sLB[f + 3];
        hl4[idx] = u;
        if (n < NN) h4g[(size_t)n * 32 + c4] = u;
    }
    int fq = t & 31;
    int ng = t >> 5;
    float4 acc[4];
#pragma unroll
    for (int j = 0; j < 4; j++) acc[j] = make_float4(0.f, 0.f, 0.f, 0.f);
    const float4* Wl4 = (const float4*)Wl;
    for (int ph = 0; ph < 2; ph++) {
        __syncthreads();
        const float4* Wg4 = (const float4*)(Wf + ph * 64 * HD);
        float4* Wld = (float4*)Wl;
#pragma unroll
        for (int r = 0; r < 8; r++) Wld[r * 256 + t] = Wg4[r * 256 + t];
        __syncthreads();
        for (int k4 = 0; k4 < 16; k4++) {
            int kb = k4 * 4;
            float4 w0 = Wl4[(kb + 0) * 32 + fq];
            float4 w1 = Wl4[(kb + 1) * 32 + fq];
            float4 w2 = Wl4[(kb + 2) * 32 + fq];
            float4 w3 = Wl4[(kb + 3) * 32 + fq];
#pragma unroll
            for (int j = 0; j < 4; j++) {
                float4 hv = hl4[(ng + 8 * j) * 32 + ph * 16 + k4];
                acc[j].x += hv.x * w0.x + hv.y * w1.x + hv.z * w2.x + hv.w * w3.x;
                acc[j].y += hv.x * w0.y + hv.y * w1.y + hv.z * w2.y + hv.w * w3.y;
                acc[j].z += hv.x * w0.z + hv.y * w1.z + hv.z * w2.z + hv.w * w3.z;
                acc[j].w += hv.x * w0.w + hv.y * w1.w + hv.z * w2.w + hv.w * w3.w;
            }
        }
    }
#pragma unroll
    for (int j = 0; j < 4; j++) {
        int n = nodeBase + ng + 8 * j;
        if (n < NN) {
            ushort4 o;
            o.x = f2h(acc[j].x); o.y = f2h(acc[j].y);
            o.z = f2h(acc[j].z); o.w = f2h(acc[j].w);
            ((ushort4*)(t0h + (size_t)n * HD))[fq] = o;
        }
    }
}

// ------- fused BN+residual+InstanceNorm + GEMM (layers 1,2); agg is fp16 -------

__global__ __launch_bounds__(256) void k_gemm_fused(const ushort* __restrict__ aggh,
                                                    const float* __restrict__ stats,
                                                    const float* __restrict__ bias,
                                                    const float* __restrict__ bng,
                                                    const float* __restrict__ bnb,
                                                    float* __restrict__ h,
                                                    const float* __restrict__ Wf,
                                                    ushort* __restrict__ t0h) {
    __shared__ float Wl[64 * HD];       // 32 KB
    __shared__ float hl[32 * HD];       // 16 KB
    __shared__ float scL[HD], shL[HD], bL[HD];
    int t = threadIdx.x;
    if (t < 128) {
        const float invN = 1.f / NN;
        float m = stats[t] * invN;
        float v = stats[128 + t] * invN - m * m;
        float sc = bng[t] * rsqrtf(v + EPSN);
        scL[t] = sc;
        shL[t] = bnb[t] - m * sc;
        bL[t] = bias[t];
    }
    __syncthreads();
    int nodeBase = blockIdx.x * 32;
    const ushort4* a4 = (const ushort4*)aggh;
    float4* h4g = (float4*)h;
    float4* hl4 = (float4*)hl;
#pragma unroll
    for (int r = 0; r < 4; r++) {
        int idx = r * 256 + t;
        int n = nodeBase + (idx >> 5);
        int c4 = idx & 31;
        float4 u = make_float4(0.f, 0.f, 0.f, 0.f);
        if (n < NN) {
            ushort4 av = a4[(size_t)n * 32 + c4];
            float4 hv = h4g[(size_t)n * 32 + c4];
            int f = c4 * 4;
            float y0 = fmaxf(0.f, h2f(av.x) + bL[f]);
            float y1 = fmaxf(0.f, h2f(av.y) + bL[f + 1]);
            float y2 = fmaxf(0.f, h2f(av.z) + bL[f + 2]);
            float y3 = fmaxf(0.f, h2f(av.w) + bL[f + 3]);
            u.x = y0 * scL[f]     + shL[f]     + hv.x;
            u.y = y1 * scL[f + 1] + shL[f + 1] + hv.y;
            u.z = y2 * scL[f + 2] + shL[f + 2] + hv.z;
            u.w = y3 * scL[f + 3] + shL[f + 3] + hv.w;
        }
        float s = u.x + u.y + u.z + u.w;
        float q = u.x * u.x + u.y * u.y + u.z * u.z + u.w * u.w;
        for (int o = 16; o; o >>= 1) { s += __shfl_xor(s, o); q += __shfl_xor(q, o); }
        float m = s * (1.f / HD);
        float var = q * (1.f / HD) - m * m;
        float rr = rsqrtf(var + EPSN);
        u.x = (u.x - m) * rr; u.y = (u.y - m) * rr;
        u.z = (u.z - m) * rr; u.w = (u.w - m) * rr;
        hl4[idx] = u;
        if (n < NN) h4g[(size_t)n * 32 + c4] = u;
    }
    int fq = t & 31;
    int ng = t >> 5;
    float4 acc[4];
#pragma unroll
    for (int j = 0; j < 4; j++) acc[j] = make_float4(0.f, 0.f, 0.f, 0.f);
    const float4* Wl4 = (const float4*)Wl;
    for (int ph = 0; ph < 2; ph++) {
        __syncthreads();
        const float4* Wg4 = (const float4*)(Wf + ph * 64 * HD);
        float4* Wld = (float4*)Wl;
#pragma unroll
        for (int r = 0; r < 8; r++) Wld[r * 256 + t] = Wg4[r * 256 + t];
        __syncthreads();
        for (int k4 = 0; k4 < 16; k4++) {
            int kb = k4 * 4;
            float4 w0 = Wl4[(kb + 0) * 32 + fq];
            float4 w1 = Wl4[(kb + 1) * 32 + fq];
            float4 w2 = Wl4[(kb + 2) * 32 + fq];
            float4 w3 = Wl4[(kb + 3) * 32 + fq];
#pragma unroll
            for (int j = 0; j < 4; j++) {
                float4 hv = hl4[(ng + 8 * j) * 32 + ph * 16 + k4];
                acc[j].x += hv.x * w0.x + hv.y * w1.x + hv.z * w2.x + hv.w * w3.x;
                acc[j].y += hv.x * w0.y + hv.y * w1.y + hv.z * w2.y + hv.w * w3.y;
                acc[j].z += hv.x * w0.z + hv.y * w1.z + hv.z * w2.z + hv.w * w3.z;
                acc[j].w += hv.x * w0.w + hv.y * w1.w + hv.z * w2.w + hv.w * w3.w;
            }
        }
    }
#pragma unroll
    for (int j = 0; j < 4; j++) {
        int n = nodeBase + ng + 8 * j;
        if (n < NN) {
            ushort4 o;
            o.x = f2h(acc[j].x); o.y = f2h(acc[j].y);
            o.z = f2h(acc[j].z); o.w = f2h(acc[j].w);
            ((ushort4*)(t0h + (size_t)n * HD))[fq] = o;
        }
    }
}

// ------- aggregate (round-9 structure, unchanged): static grid-stride, barrier-free,
// padded tail-free CSR, software-pipelined gathers; agg stored fp16 -------

__global__ __launch_bounds__(256) void k_agg(const ushort* __restrict__ t0h,
                                             const int2* __restrict__ srw,
                                             const int* __restrict__ startA,
                                             const int* __restrict__ deg,
                                             const float* __restrict__ dinv,
                                             const float* __restrict__ bias,
                                             ushort* __restrict__ aggh,
                                             float* __restrict__ stats) {
    int t = threadIdx.x;
    int f = t & 127;
    int half = t >> 7;
    float bs = bias[f];
    float rs1 = 0.f, rs2 = 0.f;
    for (int pair = blockIdx.x; pair * 2 < NN; pair += gridDim.x) {
        int i = pair * 2 + half;
        if (i < NN) {
            int s = startA[i];
            int cnt = deg[i];                 // edge-only count
            int nb = (cnt + 7) & ~7;          // padded batch count (sentinels w=0)
            int2 e[8];
            if (nb > 0) {
#pragma unroll
                for (int u = 0; u < 8; u++) e[u] = srw[s + u];
            }
            float di = dinv[i];
            float acc = di * di * h2f(t0h[i * HD + f]);   // self-loop term
            float a[8];
#pragma unroll
            for (int u = 0; u < 8; u++) a[u] = 0.f;
            for (int j = 0; j < nb; j += 8) {
                float g[8];
#pragma unroll
                for (int u = 0; u < 8; u++) g[u] = h2f(t0h[e[u].x + f]);   // gathers first
                int2 en[8];
                if (j + 8 < nb) {
#pragma unroll
                    for (int u = 0; u < 8; u++) en[u] = srw[s + j + 8 + u]; // prefetch next
                }
#pragma unroll
                for (int u = 0; u < 8; u++) a[u] += __int_as_float(e[u].y) * g[u];
                if (j + 8 < nb) {
#pragma unroll
                    for (int u = 0; u < 8; u++) e[u] = en[u];
                }
            }
            acc += ((a[0] + a[1]) + (a[2] + a[3])) + ((a[4] + a[5]) + (a[6] + a[7]));
            ushort au = f2h(acc);
            aggh[(size_t)i * HD + f] = au;
            float y = fmaxf(0.f, h2f(au) + bs);   // rounded value = what consumers see
            rs1 += y;
            rs2 += y * y;
        }
    }
    __shared__ float l1[256], l2[256];
    l1[t] = rs1; l2[t] = rs2;
    __syncthreads();
    if (t < 128) {
        atomicAdd(&stats[t], l1[t] + l1[t + 128]);
        atomicAdd(&stats[128 + t], l2[t] + l2[t + 128]);
    }
}

// ------- BN apply + residual + InstanceNorm (layer 2 only, in-place on h) -------

__global__ void k_post(const ushort* __restrict__ aggh, const float* __restrict__ stats,
                       const float* __restrict__ bias, const float* __restrict__ bng,
                       const float* __restrict__ bnb, float* __restrict__ h) {
    int node = (blockIdx.x * 256 + threadIdx.x) >> 6;
    int lane = threadIdx.x & 63;
    if (node >= NN) return;
    const float invN = 1.f / NN;
    int f0 = lane, f1 = lane + 64;
    float m0 = stats[f0] * invN, m1 = stats[f1] * invN;
    float v0 = stats[128 + f0] * invN - m0 * m0;
    float v1 = stats[128 + f1] * invN - m1 * m1;
    float sc0 = bng[f0] * rsqrtf(v0 + EPSN);
    float sc1 = bng[f1] * rsqrtf(v1 + EPSN);
    float sh0 = bnb[f0] - m0 * sc0;
    float sh1 = bnb[f1] - m1 * sc1;
    size_t base = (size_t)node * HD;
    float y0 = fmaxf(0.f, h2f(aggh[base + f0]) + bias[f0]);
    float y1 = fmaxf(0.f, h2f(aggh[base + f1]) + bias[f1]);
    float u0 = y0 * sc0 + sh0 + h[base + f0];
    float u1 = y1 * sc1 + sh1 + h[base + f1];
    float s = u0 + u1, q = u0 * u0 + u1 * u1;
    for (int o = 32; o; o >>= 1) { s += __shfl_xor(s, o); q += __shfl_xor(q, o); }
    float m = s * (1.f / HD);
    float var = q * (1.f / HD) - m * m;
    float r = rsqrtf(var + EPSN);
    h[base + f0] = (u0 - m) * r;
    h[base + f1] = (u1 - m) * r;
}

// ------- head: relu(h @ fc1 + b) -> tanh(@ fc2 + b); output dtype per flag -------

__global__ __launch_bounds__(256) void k_head(const float* __restrict__ h,
                                              const float* __restrict__ cp,
                                              const int* __restrict__ flags,
                                              void* __restrict__ outv) {
    __shared__ float W1[HD * 32];   // 16 KB, flat [k][f]
    __shared__ float B1[32], W2[64], B2[2];
    int t = threadIdx.x;
    const float* f1W = cp + O_F1W;
    for (int r = 0; r < 16; r++) W1[r * 256 + t] = f1W[r * 256 + t];
    if (t < 32) B1[t] = cp[O_F1B + t];
    if (t < 64) W2[t] = cp[O_F2W + t];
    if (t < 2) B2[t] = cp[O_F2B + t];
    __syncthreads();
    int i = blockIdx.x * 256 + t;
    if (i >= NN) return;
    float a[32];
#pragma unroll
    for (int f = 0; f < 32; f++) a[f] = B1[f];
    const float4* hr = (const float4*)(h + (size_t)i * HD);
    for (int c = 0; c < 4; c++) {
        float hk[32];
#pragma unroll
        for (int qd = 0; qd < 8; qd++) {
            float4 v = hr[c * 8 + qd];
            hk[4 * qd] = v.x; hk[4 * qd + 1] = v.y; hk[4 * qd + 2] = v.z; hk[4 * qd + 3] = v.w;
        }
#pragma unroll
        for (int kk = 0; kk < 32; kk++) {
            float hv = hk[kk];
            const float4* wr = (const float4*)(W1 + (c * 32 + kk) * 32);
#pragma unroll
            for (int qd = 0; qd < 8; qd++) {
                float4 w = wr[qd];
                a[4 * qd] += hv * w.x; a[4 * qd + 1] += hv * w.y;
                a[4 * qd + 2] += hv * w.z; a[4 * qd + 3] += hv * w.w;
            }
        }
    }
    float o0 = B2[0], o1 = B2[1];
#pragma unroll
    for (int f = 0; f < 32; f++) {
        float av = fmaxf(0.f, a[f]);
        o0 += av * W2[f * 2];
        o1 += av * W2[f * 2 + 1];
    }
    o0 = tanhf(o0); o1 = tanhf(o1);
    if (flags[1]) {
        ushort* ob = (ushort*)outv;
        ob[i * 2] = f2us(o0);
        ob[i * 2 + 1] = f2us(o1);
    } else {
        float* of = (float*)outv;
        of[i * 2] = o0;
        of[i * 2 + 1] = o1;
    }
}

// ---------------- launch ----------------

extern "C" void kernel_launch(void* const* d_in, const int* in_sizes, int n_in,
                              void* d_out, int out_size, void* d_ws, size_t ws_size,
                              hipStream_t stream) {
    const int* ei = (const int*)d_in[1];

    Ptrs ptrs;
    ptrs.p[0] = d_in[0];                                  // x
    for (int s = 1; s < 17; s++) ptrs.p[s] = d_in[s + 1]; // coord_W .. fc2_b

    char* wsp = (char*)d_ws;
    size_t off = 0;
    auto alloc = [&](size_t bytes) {
        void* p = wsp + off;
        off += (bytes + 255) & ~(size_t)255;
        return p;
    };
    float* cp     = (float*)alloc((size_t)O_TOT * 4);       // 0.62 MB canonical fp32 params
    float* h      = (float*)alloc((size_t)NN * HD * 4);     // 25.6 MB
    ushort* t0h   = (ushort*)alloc((size_t)NN * HD * 2);    // 12.8 MB fp16
    ushort* aggh  = (ushort*)alloc((size_t)NN * HD * 2);    // 12.8 MB fp16
    int* zr       = (int*)alloc((size_t)(NN + 768 + 64) * 4); // zeroed region
    float* dinv   = (float*)alloc((size_t)NN * 4);
    int2* srw     = (int2*)alloc((size_t)CAP * 8);          // 9.2 MB padded CSR
    int* startA   = (int*)alloc((size_t)NN * 4);
    int* curA     = (int*)alloc((size_t)NN * 4);

    int* deg     = zr;                      // NN ints (edge-only in-degree)
    float* stats = (float*)(zr + NN);       // 768 floats (3 layers x 256)
    int* misc    = zr + NN + 768;           // [0]=alloc cursor, [8..9]=flags
    int* flags   = misc + 8;

    const int BN_NODE = (NN + 255) / 256;   // 196
    const int BN_EDGE = (NE + 255) / 256;   // 3125
    const int BN_CONV = (O_TOT + 255) / 256;

    const float* W[3] = {cp + O_W1, cp + O_W2, cp + O_W3};
    const float* B[3] = {cp + O_B1, cp + O_B2, cp + O_B3};

    hipMemsetAsync(zr, 0, (size_t)(NN + 768 + 64) * 4, stream);
    k_conv<<<BN_CONV, 256, 0, stream>>>(ptrs, ei, (const ushort*)d_in[2], cp, flags);
    k_deg<<<BN_EDGE, 256, 0, stream>>>(ei, flags, deg);
    k_dinv_alloc<<<BN_NODE, 256, 0, stream>>>(deg, dinv, startA, curA, misc, srw);
    k_fill<<<BN_EDGE, 256, 0, stream>>>(ei, flags, dinv, curA, srw);

    k_gemm0<<<(NN + 31) / 32, 256, 0, stream>>>(cp, h, W[0], t0h);
    k_agg<<<2048, 256, 0, stream>>>(t0h, srw, startA, deg, dinv, B[0], aggh, stats);
    for (int l = 1; l < 3; l++) {
        k_gemm_fused<<<(NN + 31) / 32, 256, 0, stream>>>(aggh, stats + 256 * (l - 1),
                                                         B[l - 1], cp + O_BNG, cp + O_BNB,
                                                         h, W[l], t0h);
        k_agg<<<2048, 256, 0, stream>>>(t0h, srw, startA, deg, dinv, B[l],
                                        aggh, stats + 256 * l);
    }
    k_post<<<NN / 4, 256, 0, stream>>>(aggh, stats + 512, B[2], cp + O_BNG, cp + O_BNB, h);
    k_head<<<BN_NODE, 256, 0, stream>>>(h, cp, flags, d_out);
}